// Round 2
// baseline (622.861 us; speedup 1.0000x reference)
//
#include <hip/hip_runtime.h>
#include <hip/hip_bf16.h>
#include <math.h>

using bf16 = __hip_bfloat16;
using bf162 = __hip_bfloat162;

constexpr int NB = 4, HH = 96, WW = 96, CC = 128, GG = 8, PP = 9;
constexpr int HW = HH * WW;          // 9216
constexpr int NPIX = NB * HW;        // 36864

__device__ __forceinline__ float ld1(const float* p) { return *p; }
__device__ __forceinline__ float ld1(const bf16* p)  { return __bfloat162float(*p); }
__device__ __forceinline__ void st1(float* p, float v) { *p = v; }
__device__ __forceinline__ void st1(bf16* p, float v)  { *p = __float2bfloat16(v); }
__device__ __forceinline__ float b2f(bf16 v) { return __bfloat162float(v); }
__device__ __forceinline__ bf16 f2b(float v) { return __float2bfloat16(v); }
__device__ __forceinline__ float gelu_exact(float v) {
    return 0.5f * v * (1.0f + erff(v * 0.7071067811865475f));
}

// ---------------- LayerNorm over C=128, one wave per pixel, 2 ch/lane
template<typename TI, typename TO>
__global__ __launch_bounds__(256) void ln_kernel(
    const TI* __restrict__ X, const float* __restrict__ g,
    const float* __restrict__ b, TO* __restrict__ out)
{
    int wave = (blockIdx.x * 256 + threadIdx.x) >> 6;
    int lane = threadIdx.x & 63;
    if (wave >= NPIX) return;
    const TI* xp = X + (size_t)wave * 128 + 2 * lane;
    float v0 = ld1(xp), v1 = ld1(xp + 1);
    float s = v0 + v1, q = v0 * v0 + v1 * v1;
    #pragma unroll
    for (int o = 32; o; o >>= 1) { s += __shfl_xor(s, o); q += __shfl_xor(q, o); }
    float mean = s * (1.0f / 128.0f);
    float rstd = rsqrtf(q * (1.0f / 128.0f) - mean * mean + 1e-5f);
    float g0 = g[2 * lane], g1 = g[2 * lane + 1];
    float b0 = b[2 * lane], b1 = b[2 * lane + 1];
    TO* op = out + (size_t)wave * 128 + 2 * lane;
    st1(op,     (v0 - mean) * rstd * g0 + b0);
    st1(op + 1, (v1 - mean) * rstd * g1 + b1);
}

// ---------------- depthwise 3x3 conv (SAME, zero pad) + LN + exact GELU. wave/pixel
__global__ __launch_bounds__(256) void dwconv_ln_gelu_kernel(
    const bf16* __restrict__ xln, const float* __restrict__ dwk,
    const float* __restrict__ dwb, const float* __restrict__ gam,
    const float* __restrict__ bet, bf16* __restrict__ out)
{
    int wave = (blockIdx.x * 256 + threadIdx.x) >> 6;
    int lane = threadIdx.x & 63;
    if (wave >= NPIX) return;
    int n = wave / HW; int rem = wave % HW;
    int y = rem / WW;  int x = rem % WW;
    const bf162* xp = (const bf162*)xln;
    float a0 = 0.f, a1 = 0.f;
    #pragma unroll
    for (int ky = 0; ky < 3; ++ky) {
        int yy = y + ky - 1;
        if (yy < 0 || yy >= HH) continue;
        #pragma unroll
        for (int kx = 0; kx < 3; ++kx) {
            int xx = x + kx - 1;
            if (xx < 0 || xx >= WW) continue;
            bf162 v = xp[((size_t)(n * HH + yy) * WW + xx) * 64 + lane];
            const float* w = dwk + (ky * 3 + kx) * CC + 2 * lane;
            a0 = fmaf(b2f(v.x), w[0], a0);
            a1 = fmaf(b2f(v.y), w[1], a1);
        }
    }
    a0 += dwb[2 * lane]; a1 += dwb[2 * lane + 1];
    float s = a0 + a1, q = a0 * a0 + a1 * a1;
    #pragma unroll
    for (int o = 32; o; o >>= 1) { s += __shfl_xor(s, o); q += __shfl_xor(q, o); }
    float mean = s * (1.0f / 128.0f);
    float rstd = rsqrtf(q * (1.0f / 128.0f) - mean * mean + 1e-5f);
    float h0 = gelu_exact((a0 - mean) * rstd * gam[2 * lane]     + bet[2 * lane]);
    float h1 = gelu_exact((a1 - mean) * rstd * gam[2 * lane + 1] + bet[2 * lane + 1]);
    bf162 o2; o2.x = f2b(h0); o2.y = f2b(h1);
    ((bf162*)out)[(size_t)wave * 64 + lane] = o2;
}

// ---------------- softmax over P=9, thread per (pixel, group). In-place (bf16).
__global__ __launch_bounds__(256) void softmax9_kernel(bf16* __restrict__ m)
{
    int t = blockIdx.x * 256 + threadIdx.x;
    if (t >= NPIX * GG) return;
    bf16* p = m + (size_t)t * 9;
    float v[9]; float mx = -1e30f;
    #pragma unroll
    for (int i = 0; i < 9; ++i) { v[i] = b2f(p[i]); mx = fmaxf(mx, v[i]); }
    float s = 0.f;
    #pragma unroll
    for (int i = 0; i < 9; ++i) { v[i] = expf(v[i] - mx); s += v[i]; }
    float r = 1.0f / s;
    #pragma unroll
    for (int i = 0; i < 9; ++i) p[i] = f2b(v[i] * r);
}

// ---------------- DCNv3 core: thread per (pixel, channel), all bf16 intermediates
__device__ __forceinline__ float samp(const bf16* __restrict__ xb, int y, int x) {
    return (y >= 0 && y < HH && x >= 0 && x < WW)
        ? __bfloat162float(xb[((size_t)y * WW + x) * CC]) : 0.f;
}

__global__ __launch_bounds__(256) void dcn_core_kernel(
    const bf16* __restrict__ xproj, const bf16* __restrict__ off,
    const bf16* __restrict__ msk, bf16* __restrict__ out)
{
    int t = blockIdx.x * 256 + threadIdx.x;        // NPIX*128
    int pix = t >> 7, c = t & 127, g = c >> 4;
    int n = pix / HW; int rem = pix % HW;
    int iy = rem / WW; int ix = rem % WW;
    const bf16* op = off + (size_t)pix * (GG * PP * 2) + g * (PP * 2);
    const bf16* mp = msk + (size_t)pix * (GG * PP) + g * PP;
    const bf16* xb = xproj + (size_t)n * HW * CC + c;
    float acc = 0.f;
    #pragma unroll
    for (int p = 0; p < 9; ++p) {
        int kx = p / 3 - 1, ky = p % 3 - 1;   // x varies slowest, y fastest (torch meshgrid 'ij')
        float px = (float)(ix + kx) + b2f(op[2 * p]);
        float py = (float)(iy + ky) + b2f(op[2 * p + 1]);
        float mw = b2f(mp[p]);
        float fx0 = floorf(px), fy0 = floorf(py);
        int x0 = (int)fx0, y0 = (int)fy0;
        float fx = px - fx0, fy = py - fy0;
        float s = 0.f;
        s += (1.f - fy) * (1.f - fx) * samp(xb, y0, x0);
        s += (1.f - fy) * fx         * samp(xb, y0, x0 + 1);
        s += fy * (1.f - fx)         * samp(xb, y0 + 1, x0);
        s += fy * fx                 * samp(xb, y0 + 1, x0 + 1);
        acc = fmaf(mw, s, acc);
    }
    out[(size_t)pix * CC + c] = f2b(acc);
}

// ---------------- generic GEMM: Out[M,N] = act(A[M,K] @ W[K,N] + bias) (+R)
// BM=BN=64, BK=32, 256 threads, 4x4 per-thread register tile, f32 accumulate.
// A: bf16 intermediate; W/bias: f32 weights; R: residual (f32 input or bf16); Out: bf16 or f32.
template<typename TA, typename TR, typename TO>
__global__ __launch_bounds__(256) void gemm_kernel(
    const TA* __restrict__ A, const float* __restrict__ W,
    const float* __restrict__ bias, const TR* __restrict__ R,
    TO* __restrict__ Out, int M, int Nn, int K, int act)
{
    __shared__ float As[64][33];
    __shared__ float Bs[32][65];
    int bm = blockIdx.y * 64;
    int bn = blockIdx.x * 64;
    int tid = threadIdx.x;
    int tx = tid & 15, ty = tid >> 4;
    float acc[4][4] = {};

    for (int k0 = 0; k0 < K; k0 += 32) {
        { // A tile 64x32: thread loads 8 contiguous
            int r = tid >> 2, c = (tid & 3) * 8;
            const TA* ap = A + (size_t)(bm + r) * K + k0 + c;
            #pragma unroll
            for (int j = 0; j < 8; ++j) As[r][c + j] = ld1(ap + j);
        }
        { // B tile 32x64: thread loads 8 contiguous, N-guarded
            int r = tid >> 3, c = (tid & 7) * 8;
            if (bn + c + 8 <= Nn) {
                const float* wp = W + (size_t)(k0 + r) * Nn + bn + c;
                #pragma unroll
                for (int j = 0; j < 8; ++j) Bs[r][c + j] = wp[j];
            } else {
                #pragma unroll
                for (int j = 0; j < 8; ++j) {
                    int nn = bn + c + j;
                    Bs[r][c + j] = (nn < Nn) ? W[(size_t)(k0 + r) * Nn + nn] : 0.f;
                }
            }
        }
        __syncthreads();
        #pragma unroll
        for (int k = 0; k < 32; ++k) {
            float a[4], b[4];
            #pragma unroll
            for (int i = 0; i < 4; ++i) a[i] = As[ty * 4 + i][k];
            #pragma unroll
            for (int j = 0; j < 4; ++j) b[j] = Bs[k][tx * 4 + j];
            #pragma unroll
            for (int i = 0; i < 4; ++i)
                #pragma unroll
                for (int j = 0; j < 4; ++j)
                    acc[i][j] = fmaf(a[i], b[j], acc[i][j]);
        }
        __syncthreads();
    }
    #pragma unroll
    for (int i = 0; i < 4; ++i) {
        int m = bm + ty * 4 + i;
        #pragma unroll
        for (int j = 0; j < 4; ++j) {
            int nn = bn + tx * 4 + j;
            if (nn >= Nn) continue;
            float v = acc[i][j] + bias[nn];
            if (act == 1) v = gelu_exact(v);
            if (R) v += ld1(R + (size_t)m * Nn + nn);
            st1(Out + (size_t)m * Nn + nn, v);
        }
    }
}

extern "C" void kernel_launch(void* const* d_in, const int* in_sizes, int n_in,
                              void* d_out, int out_size, void* d_ws, size_t ws_size,
                              hipStream_t stream)
{
    const float* x     = (const float*)d_in[0];
    const float* ln1g  = (const float*)d_in[1];
    const float* ln1b  = (const float*)d_in[2];
    const float* w_in  = (const float*)d_in[3];
    const float* b_in  = (const float*)d_in[4];
    const float* dw_k  = (const float*)d_in[5];
    const float* dw_b  = (const float*)d_in[6];
    const float* dwg   = (const float*)d_in[7];
    const float* dwb   = (const float*)d_in[8];
    const float* w_off = (const float*)d_in[9];
    const float* b_off = (const float*)d_in[10];
    const float* w_msk = (const float*)d_in[11];
    const float* b_msk = (const float*)d_in[12];
    const float* w_out = (const float*)d_in[13];
    const float* b_out = (const float*)d_in[14];
    const float* ln2g  = (const float*)d_in[15];
    const float* ln2b  = (const float*)d_in[16];
    const float* w1    = (const float*)d_in[17];
    const float* b1    = (const float*)d_in[18];
    const float* w2    = (const float*)d_in[19];
    const float* b2    = (const float*)d_in[20];
    float* out = (float*)d_out;

    // workspace layout (bf16 elems), overlapped lifetimes — 968 bf16/pixel = 71.4 MB:
    //   xln(128)->ycore | xproj(128)->h2 | x1(128)->xres | mskr(72) | offr(144)->h1(512)
    bf16* ws = (bf16*)d_ws;
    bf16* xln   = ws;
    bf16* xproj = xln   + (size_t)NPIX * 128;
    bf16* x1    = xproj + (size_t)NPIX * 128;
    bf16* mskr  = x1    + (size_t)NPIX * 128;
    bf16* offr  = mskr  + (size_t)NPIX * 72;
    bf16* h1    = offr;  // overlays offr (dead after dcn), 512/pix
    bf16* ycore = xln;   // reuse (xln dead after dwconv)
    bf16* xres  = x1;    // reuse (x1 dead after mask GEMM)
    bf16* h2    = xproj; // reuse (xproj dead after dcn)

    const int M = NPIX;
    dim3 blk(256);

    // 1. xln = LN1(x)                         f32 -> bf16
    ln_kernel<float, bf16><<<NPIX / 4, blk, 0, stream>>>(x, ln1g, ln1b, xln);
    // 2. xproj = xln @ w_in + b_in
    gemm_kernel<bf16, float, bf16><<<dim3(2, M / 64), blk, 0, stream>>>(
        xln, w_in, b_in, nullptr, xproj, M, 128, 128, 0);
    // 3. x1 = gelu(LN(dwconv(xln) + dw_b))
    dwconv_ln_gelu_kernel<<<NPIX / 4, blk, 0, stream>>>(xln, dw_k, dw_b, dwg, dwb, x1);
    // 4. offr = x1 @ w_off + b_off
    gemm_kernel<bf16, float, bf16><<<dim3(3, M / 64), blk, 0, stream>>>(
        x1, w_off, b_off, nullptr, offr, M, 144, 128, 0);
    // 5. mskr = x1 @ w_msk + b_msk
    gemm_kernel<bf16, float, bf16><<<dim3(2, M / 64), blk, 0, stream>>>(
        x1, w_msk, b_msk, nullptr, mskr, M, 72, 128, 0);
    // 6. msk = softmax9(mskr), in place
    softmax9_kernel<<<(NPIX * GG + 255) / 256, blk, 0, stream>>>(mskr);
    // 7. ycore = dcnv3(xproj, offr, mskr)
    dcn_core_kernel<<<NPIX * CC / 256, blk, 0, stream>>>(xproj, offr, mskr, ycore);
    // 8. xres = x + ycore @ w_out + b_out     (R = x, f32)
    gemm_kernel<bf16, float, bf16><<<dim3(2, M / 64), blk, 0, stream>>>(
        ycore, w_out, b_out, x, xres, M, 128, 128, 0);
    // 9. h2 = LN2(xres)                       bf16 -> bf16
    ln_kernel<bf16, bf16><<<NPIX / 4, blk, 0, stream>>>(xres, ln2g, ln2b, h2);
    // 10. h1 = gelu(h2 @ w1 + b1)
    gemm_kernel<bf16, float, bf16><<<dim3(8, M / 64), blk, 0, stream>>>(
        h2, w1, b1, nullptr, h1, M, 512, 128, 1);
    // 11. out = xres + h1 @ w2 + b2           (R = xres bf16, Out = f32)
    gemm_kernel<bf16, bf16, float><<<dim3(2, M / 64), blk, 0, stream>>>(
        h1, w2, b2, xres, out, M, 128, 512, 0);
}

// Round 3
// 255.939 us; speedup vs baseline: 2.4336x; 2.4336x over previous
//
#include <hip/hip_runtime.h>
#include <hip/hip_bf16.h>
#include <math.h>

using bf16 = __hip_bfloat16;
using bf162 = __hip_bfloat162;

typedef __bf16 bf16x8 __attribute__((ext_vector_type(8)));
typedef float floatx4 __attribute__((ext_vector_type(4)));

constexpr int NB = 4, HH = 96, WW = 96, CC = 128, GG = 8, PP = 9;
constexpr int HW = HH * WW;          // 9216
constexpr int NPIX = NB * HW;        // 36864

__device__ __forceinline__ float ld1(const float* p) { return *p; }
__device__ __forceinline__ float ld1(const bf16* p)  { return __bfloat162float(*p); }
__device__ __forceinline__ void st1(float* p, float v) { *p = v; }
__device__ __forceinline__ void st1(bf16* p, float v)  { *p = __float2bfloat16(v); }
__device__ __forceinline__ float b2f(bf16 v) { return __bfloat162float(v); }
__device__ __forceinline__ bf16 f2b(float v) { return __float2bfloat16(v); }
__device__ __forceinline__ float gelu_exact(float v) {
    return 0.5f * v * (1.0f + erff(v * 0.7071067811865475f));
}

// ---------------- one-time weight prep: f32 W[K][N] -> bf16 Wt[N][K]
struct PrepArgs {
    const float* src[6];
    bf16* dst[6];
    int K[6], N[6];
    int cum[7];
};

__global__ __launch_bounds__(256) void prep_weights(PrepArgs pa, int total)
{
    int t = blockIdx.x * 256 + threadIdx.x;
    if (t >= total) return;
    int i = 0;
    #pragma unroll
    for (int j = 0; j < 5; ++j) if (t >= pa.cum[j + 1]) i = j + 1;
    int e = t - pa.cum[i];
    int Ki = pa.K[i], Ni = pa.N[i];
    int n = e / Ki, k = e - n * Ki;
    pa.dst[i][e] = f2b(pa.src[i][(size_t)k * Ni + n]);
}

// ---------------- LayerNorm over C=128, one wave per pixel, 2 ch/lane
template<typename TI, typename TO>
__global__ __launch_bounds__(256) void ln_kernel(
    const TI* __restrict__ X, const float* __restrict__ g,
    const float* __restrict__ b, TO* __restrict__ out)
{
    int wave = (blockIdx.x * 256 + threadIdx.x) >> 6;
    int lane = threadIdx.x & 63;
    if (wave >= NPIX) return;
    const TI* xp = X + (size_t)wave * 128 + 2 * lane;
    float v0 = ld1(xp), v1 = ld1(xp + 1);
    float s = v0 + v1, q = v0 * v0 + v1 * v1;
    #pragma unroll
    for (int o = 32; o; o >>= 1) { s += __shfl_xor(s, o); q += __shfl_xor(q, o); }
    float mean = s * (1.0f / 128.0f);
    float rstd = rsqrtf(q * (1.0f / 128.0f) - mean * mean + 1e-5f);
    float g0 = g[2 * lane], g1 = g[2 * lane + 1];
    float b0 = b[2 * lane], b1 = b[2 * lane + 1];
    TO* op = out + (size_t)wave * 128 + 2 * lane;
    st1(op,     (v0 - mean) * rstd * g0 + b0);
    st1(op + 1, (v1 - mean) * rstd * g1 + b1);
}

// ---------------- depthwise 3x3 conv (SAME, zero pad) + LN + exact GELU. wave/pixel
__global__ __launch_bounds__(256) void dwconv_ln_gelu_kernel(
    const bf16* __restrict__ xln, const float* __restrict__ dwk,
    const float* __restrict__ dwb, const float* __restrict__ gam,
    const float* __restrict__ bet, bf16* __restrict__ out)
{
    int wave = (blockIdx.x * 256 + threadIdx.x) >> 6;
    int lane = threadIdx.x & 63;
    if (wave >= NPIX) return;
    int n = wave / HW; int rem = wave % HW;
    int y = rem / WW;  int x = rem % WW;
    const bf162* xp = (const bf162*)xln;
    float a0 = 0.f, a1 = 0.f;
    #pragma unroll
    for (int ky = 0; ky < 3; ++ky) {
        int yy = y + ky - 1;
        if (yy < 0 || yy >= HH) continue;
        #pragma unroll
        for (int kx = 0; kx < 3; ++kx) {
            int xx = x + kx - 1;
            if (xx < 0 || xx >= WW) continue;
            bf162 v = xp[((size_t)(n * HH + yy) * WW + xx) * 64 + lane];
            const float* w = dwk + (ky * 3 + kx) * CC + 2 * lane;
            a0 = fmaf(b2f(v.x), w[0], a0);
            a1 = fmaf(b2f(v.y), w[1], a1);
        }
    }
    a0 += dwb[2 * lane]; a1 += dwb[2 * lane + 1];
    float s = a0 + a1, q = a0 * a0 + a1 * a1;
    #pragma unroll
    for (int o = 32; o; o >>= 1) { s += __shfl_xor(s, o); q += __shfl_xor(q, o); }
    float mean = s * (1.0f / 128.0f);
    float rstd = rsqrtf(q * (1.0f / 128.0f) - mean * mean + 1e-5f);
    float h0 = gelu_exact((a0 - mean) * rstd * gam[2 * lane]     + bet[2 * lane]);
    float h1 = gelu_exact((a1 - mean) * rstd * gam[2 * lane + 1] + bet[2 * lane + 1]);
    bf162 o2; o2.x = f2b(h0); o2.y = f2b(h1);
    ((bf162*)out)[(size_t)wave * 64 + lane] = o2;
}

// ---------------- softmax over P=9, thread per (pixel, group). In-place (bf16).
__global__ __launch_bounds__(256) void softmax9_kernel(bf16* __restrict__ m)
{
    int t = blockIdx.x * 256 + threadIdx.x;
    if (t >= NPIX * GG) return;
    bf16* p = m + (size_t)t * 9;
    float v[9]; float mx = -1e30f;
    #pragma unroll
    for (int i = 0; i < 9; ++i) { v[i] = b2f(p[i]); mx = fmaxf(mx, v[i]); }
    float s = 0.f;
    #pragma unroll
    for (int i = 0; i < 9; ++i) { v[i] = expf(v[i] - mx); s += v[i]; }
    float r = 1.0f / s;
    #pragma unroll
    for (int i = 0; i < 9; ++i) p[i] = f2b(v[i] * r);
}

// ---------------- DCNv3 core: wave per pixel, two-phase (LDS bilinear records)
__global__ __launch_bounds__(256) void dcn_core_kernel(
    const bf16* __restrict__ xproj, const bf16* __restrict__ off,
    const bf16* __restrict__ msk, bf16* __restrict__ out)
{
    __shared__ int4   sOff[4][72];
    __shared__ float4 sW[4][72];
    int wv = threadIdx.x >> 6;
    int lane = threadIdx.x & 63;
    int pix = blockIdx.x * 4 + wv;
    int n = pix / HW; int rem = pix % HW;
    int iy = rem / WW; int ix = rem % WW;

    // phase 1: 72 (group,point) records per pixel
    for (int e = lane; e < 72; e += 64) {
        int g = e / 9, p = e - 9 * g;
        float ox = b2f(off[(size_t)pix * 144 + g * 18 + 2 * p]);
        float oy = b2f(off[(size_t)pix * 144 + g * 18 + 2 * p + 1]);
        float mw = b2f(msk[(size_t)pix * 72 + e]);
        int kx = p / 3 - 1, ky = p % 3 - 1;  // torch meshgrid 'ij': x slowest
        float px = (float)(ix + kx) + ox;
        float py = (float)(iy + ky) + oy;
        float fx0 = floorf(px), fy0 = floorf(py);
        int x0 = (int)fx0, y0 = (int)fy0;
        float fx = px - fx0, fy = py - fy0;
        bool vx0 = (x0 >= 0) & (x0 < WW), vx1 = (x0 + 1 >= 0) & (x0 + 1 < WW);
        bool vy0 = (y0 >= 0) & (y0 < HH), vy1 = (y0 + 1 >= 0) & (y0 + 1 < HH);
        float w00 = (1.f - fy) * (1.f - fx) * mw * (vy0 && vx0 ? 1.f : 0.f);
        float w01 = (1.f - fy) * fx         * mw * (vy0 && vx1 ? 1.f : 0.f);
        float w10 = fy * (1.f - fx)         * mw * (vy1 && vx0 ? 1.f : 0.f);
        float w11 = fy * fx                 * mw * (vy1 && vx1 ? 1.f : 0.f);
        int x0c = min(max(x0, 0), WW - 1), x1c = min(max(x0 + 1, 0), WW - 1);
        int y0c = min(max(y0, 0), HH - 1), y1c = min(max(y0 + 1, 0), HH - 1);
        sOff[wv][e] = make_int4((y0c * WW + x0c) * CC, (y0c * WW + x1c) * CC,
                                (y1c * WW + x0c) * CC, (y1c * WW + x1c) * CC);
        sW[wv][e] = make_float4(w00, w01, w10, w11);
    }
    __syncthreads();

    // phase 2: lane = channel pair
    const bf16* xb = xproj + (size_t)n * HW * CC + 2 * lane;
    int gbase = (lane >> 3) * 9;
    float a0 = 0.f, a1 = 0.f;
    #pragma unroll
    for (int p = 0; p < 9; ++p) {
        int4 o = sOff[wv][gbase + p];
        float4 w = sW[wv][gbase + p];
        bf162 v00 = *(const bf162*)(xb + o.x);
        bf162 v01 = *(const bf162*)(xb + o.y);
        bf162 v10 = *(const bf162*)(xb + o.z);
        bf162 v11 = *(const bf162*)(xb + o.w);
        a0 += w.x * b2f(v00.x) + w.y * b2f(v01.x) + w.z * b2f(v10.x) + w.w * b2f(v11.x);
        a1 += w.x * b2f(v00.y) + w.y * b2f(v01.y) + w.z * b2f(v10.y) + w.w * b2f(v11.y);
    }
    bf162 o2; o2.x = f2b(a0); o2.y = f2b(a1);
    ((bf162*)out)[(size_t)pix * 64 + lane] = o2;
}

// ---------------- MFMA GEMM: Out[M,N] = act(A[M,K] @ W[K,N] + bias) (+R)
// A bf16 row-major [M,K]; Wt bf16 TRANSPOSED [N,K]; bias f32.
// Block 256 = 4 waves; tile BM=64,BN=64,BK=64; wave w: rows w*16..w*16+15, 4 col-tiles.
template<typename TR, typename TO>
__global__ __launch_bounds__(256) void gemm_mfma_kernel(
    const bf16* __restrict__ A, const bf16* __restrict__ Wt,
    const float* __restrict__ bias, const TR* __restrict__ R,
    TO* __restrict__ Out, int M, int Nn, int K, int act)
{
    __shared__ __bf16 As[64][72];   // row stride 144B (16B multiple, conflict-light)
    __shared__ __bf16 Bs[64][72];   // Bs[n][k]
    int tid = threadIdx.x;
    int wv = tid >> 6, lane = tid & 63;
    int bm = blockIdx.y * 64, bn = blockIdx.x * 64;
    int mI = lane & 15, q = lane >> 4;
    floatx4 acc[4] = {};

    for (int k0 = 0; k0 < K; k0 += 64) {
        #pragma unroll
        for (int cc = 0; cc < 2; ++cc) {
            int ch = tid * 2 + cc;               // 0..511
            int row = ch >> 3, ko = (ch & 7) * 8;
            uint4 av = *reinterpret_cast<const uint4*>(A + (size_t)(bm + row) * K + k0 + ko);
            *reinterpret_cast<uint4*>(&As[row][ko]) = av;
            int ng = bn + row;
            uint4 bv = make_uint4(0, 0, 0, 0);
            if (ng < Nn) bv = *reinterpret_cast<const uint4*>(Wt + (size_t)ng * K + k0 + ko);
            *reinterpret_cast<uint4*>(&Bs[row][ko]) = bv;
        }
        __syncthreads();
        #pragma unroll
        for (int kk = 0; kk < 64; kk += 32) {
            bf16x8 a = *reinterpret_cast<const bf16x8*>(&As[wv * 16 + mI][kk + q * 8]);
            #pragma unroll
            for (int t = 0; t < 4; ++t) {
                bf16x8 b = *reinterpret_cast<const bf16x8*>(&Bs[t * 16 + mI][kk + q * 8]);
                acc[t] = __builtin_amdgcn_mfma_f32_16x16x32_bf16(a, b, acc[t], 0, 0, 0);
            }
        }
        __syncthreads();
    }
    // epilogue: D elem (row = q*4+r, col = lane&15) per tile
    int row0 = bm + wv * 16 + q * 4;
    #pragma unroll
    for (int t = 0; t < 4; ++t) {
        int col = bn + t * 16 + mI;
        if (col >= Nn) continue;
        float bs = bias[col];
        #pragma unroll
        for (int r = 0; r < 4; ++r) {
            int row = row0 + r;
            float v = acc[t][r] + bs;
            if (act == 1) v = gelu_exact(v);
            if (R) v += ld1(R + (size_t)row * Nn + col);
            st1(Out + (size_t)row * Nn + col, v);
        }
    }
}

extern "C" void kernel_launch(void* const* d_in, const int* in_sizes, int n_in,
                              void* d_out, int out_size, void* d_ws, size_t ws_size,
                              hipStream_t stream)
{
    const float* x     = (const float*)d_in[0];
    const float* ln1g  = (const float*)d_in[1];
    const float* ln1b  = (const float*)d_in[2];
    const float* w_in  = (const float*)d_in[3];
    const float* b_in  = (const float*)d_in[4];
    const float* dw_k  = (const float*)d_in[5];
    const float* dw_b  = (const float*)d_in[6];
    const float* dwg   = (const float*)d_in[7];
    const float* dwb   = (const float*)d_in[8];
    const float* w_off = (const float*)d_in[9];
    const float* b_off = (const float*)d_in[10];
    const float* w_msk = (const float*)d_in[11];
    const float* b_msk = (const float*)d_in[12];
    const float* w_out = (const float*)d_in[13];
    const float* b_out = (const float*)d_in[14];
    const float* ln2g  = (const float*)d_in[15];
    const float* ln2b  = (const float*)d_in[16];
    const float* w1    = (const float*)d_in[17];
    const float* b1    = (const float*)d_in[18];
    const float* w2    = (const float*)d_in[19];
    const float* b2    = (const float*)d_in[20];
    float* out = (float*)d_out;

    // activations (bf16), overlapped lifetimes — 968 bf16/pixel:
    bf16* ws = (bf16*)d_ws;
    bf16* xln   = ws;
    bf16* xproj = xln   + (size_t)NPIX * 128;
    bf16* x1    = xproj + (size_t)NPIX * 128;
    bf16* mskr  = x1    + (size_t)NPIX * 128;
    bf16* offr  = mskr  + (size_t)NPIX * 72;
    bf16* h1    = offr;  // overlays offr (dead after dcn), 512/pix
    bf16* ycore = xln;   // xln dead after dwconv
    bf16* xres  = x1;    // x1 dead after mask GEMM
    bf16* h2    = xproj; // xproj dead after dcn
    // transposed bf16 weights after activations
    bf16* wT    = ws + (size_t)NPIX * 968;
    bf16* w_inT  = wT;                  // 128x128
    bf16* w_offT = w_inT  + 16384;      // 144x128
    bf16* w_mskT = w_offT + 18432;      // 72x128
    bf16* w_outT = w_mskT + 9216;       // 128x128
    bf16* w1T    = w_outT + 16384;      // 512x128
    bf16* w2T    = w1T    + 65536;      // 128x512
    const int WTOT = 191488;

    PrepArgs pa;
    pa.src[0] = w_in;  pa.dst[0] = w_inT;  pa.K[0] = 128; pa.N[0] = 128;
    pa.src[1] = w_off; pa.dst[1] = w_offT; pa.K[1] = 128; pa.N[1] = 144;
    pa.src[2] = w_msk; pa.dst[2] = w_mskT; pa.K[2] = 128; pa.N[2] = 72;
    pa.src[3] = w_out; pa.dst[3] = w_outT; pa.K[3] = 128; pa.N[3] = 128;
    pa.src[4] = w1;    pa.dst[4] = w1T;    pa.K[4] = 128; pa.N[4] = 512;
    pa.src[5] = w2;    pa.dst[5] = w2T;    pa.K[5] = 512; pa.N[5] = 128;
    pa.cum[0] = 0;     pa.cum[1] = 16384;  pa.cum[2] = 34816; pa.cum[3] = 44032;
    pa.cum[4] = 60416; pa.cum[5] = 125952; pa.cum[6] = 191488;

    const int M = NPIX;
    dim3 blk(256);

    // 0. weight prep
    prep_weights<<<(WTOT + 255) / 256, blk, 0, stream>>>(pa, WTOT);
    // 1. xln = LN1(x)
    ln_kernel<float, bf16><<<NPIX / 4, blk, 0, stream>>>(x, ln1g, ln1b, xln);
    // 2. xproj = xln @ w_in + b_in
    gemm_mfma_kernel<float, bf16><<<dim3(2, M / 64), blk, 0, stream>>>(
        xln, w_inT, b_in, (const float*)nullptr, xproj, M, 128, 128, 0);
    // 3. x1 = gelu(LN(dwconv(xln) + dw_b))
    dwconv_ln_gelu_kernel<<<NPIX / 4, blk, 0, stream>>>(xln, dw_k, dw_b, dwg, dwb, x1);
    // 4. offr = x1 @ w_off + b_off
    gemm_mfma_kernel<float, bf16><<<dim3(3, M / 64), blk, 0, stream>>>(
        x1, w_offT, b_off, (const float*)nullptr, offr, M, 144, 128, 0);
    // 5. mskr = x1 @ w_msk + b_msk
    gemm_mfma_kernel<float, bf16><<<dim3(2, M / 64), blk, 0, stream>>>(
        x1, w_mskT, b_msk, (const float*)nullptr, mskr, M, 72, 128, 0);
    // 6. msk = softmax9(mskr), in place
    softmax9_kernel<<<(NPIX * GG + 255) / 256, blk, 0, stream>>>(mskr);
    // 7. ycore = dcnv3(xproj, offr, mskr)
    dcn_core_kernel<<<NPIX / 4, blk, 0, stream>>>(xproj, offr, mskr, ycore);
    // 8. xres = x + ycore @ w_out + b_out
    gemm_mfma_kernel<float, bf16><<<dim3(2, M / 64), blk, 0, stream>>>(
        ycore, w_outT, b_out, x, xres, M, 128, 128, 0);
    // 9. h2 = LN2(xres)
    ln_kernel<bf16, bf16><<<NPIX / 4, blk, 0, stream>>>(xres, ln2g, ln2b, h2);
    // 10. h1 = gelu(h2 @ w1 + b1)
    gemm_mfma_kernel<float, bf16><<<dim3(8, M / 64), blk, 0, stream>>>(
        h2, w1T, b1, (const float*)nullptr, h1, M, 512, 128, 1);
    // 11. out = xres + h1 @ w2 + b2
    gemm_mfma_kernel<bf16, float><<<dim3(2, M / 64), blk, 0, stream>>>(
        h1, w2T, b2, xres, out, M, 128, 512, 0);
}